// Round 2
// baseline (1180.569 us; speedup 1.0000x reference)
//
#include <hip/hip_runtime.h>
#include <stdint.h>

typedef __bf16 bf16;
typedef bf16 bf16x8 __attribute__((ext_vector_type(8)));
typedef float f32x4 __attribute__((ext_vector_type(4)));
typedef unsigned short u16x8 __attribute__((ext_vector_type(8)));

// ---------------------------------------------------------------------------
// Prep: convert+transpose weights w1..w12 from fp32 (O,C,K) to bf16 [O][K*C]
// (r = k*C + c ordering)
// ---------------------------------------------------------------------------
template<int C>
__device__ inline void cvt_one(const float* __restrict__ src, bf16* __restrict__ dst,
                               int e, int base) {
    int local = e - base;
    constexpr int CK = C * 10;
    int o = local / CK;
    int rem = local - o * CK;
    int k = rem / C;
    int c = rem & (C - 1);
    dst[e] = (bf16)src[(o * C + c) * 10 + k];
}

__global__ __launch_bounds__(256) void prep_w(
    const float* w1, const float* w2, const float* w3, const float* w4,
    const float* w5, const float* w6, const float* w7, const float* w8,
    const float* w9, const float* w10, const float* w11, const float* w12,
    bf16* __restrict__ dst)
{
    int e = blockIdx.x * 256 + threadIdx.x;
    if (e >= 16343040) return;
    if      (e <    40960) cvt_one< 64>(w1,  dst, e, 0);
    else if (e <   122880) cvt_one< 64>(w2,  dst, e, 40960);
    else if (e <   286720) cvt_one<128>(w3,  dst, e, 122880);
    else if (e <   614400) cvt_one<128>(w4,  dst, e, 286720);
    else if (e <  1269760) cvt_one<256>(w5,  dst, e, 614400);
    else if (e <  1925120) cvt_one<256>(w6,  dst, e, 1269760);
    else if (e <  3235840) cvt_one<256>(w7,  dst, e, 1925120);
    else if (e <  5857280) cvt_one<512>(w8,  dst, e, 3235840);
    else if (e <  8478720) cvt_one<512>(w9,  dst, e, 5857280);
    else if (e < 11100160) cvt_one<512>(w10, dst, e, 8478720);
    else if (e < 13721600) cvt_one<512>(w11, dst, e, 11100160);
    else                   cvt_one<512>(w12, dst, e, 13721600);
}

// ---------------------------------------------------------------------------
// conv0: C=3, K=10, O=64, fp32 VALU. out: [2][81920][64] bf16
// ---------------------------------------------------------------------------
__global__ __launch_bounds__(256) void conv0_kernel(
    const float* __restrict__ x, const float* __restrict__ w0,
    const float* __restrict__ b0, const int* __restrict__ table,
    bf16* __restrict__ out)
{
    const int N = 81920;
    __shared__ float wls[30][64];
    __shared__ float bls[64];
    int tid = threadIdx.x;
    for (int i = tid; i < 1920; i += 256) {
        int o = i / 30, ck = i - o * 30;
        wls[ck][o] = w0[i];
    }
    if (tid < 64) bls[tid] = b0[tid];
    __syncthreads();

    int p = blockIdx.x * 256 + tid;
    int b = p >= N;
    int n = p - b * N;
    int idx[10];
    const int* trow = table + n * 10;
#pragma unroll
    for (int k = 0; k < 10; k++) idx[k] = trow[k];
    float xv[30];
#pragma unroll
    for (int c = 0; c < 3; c++)
#pragma unroll
        for (int k = 0; k < 10; k++)
            xv[c * 10 + k] = x[(b * 3 + c) * N + idx[k]];

    float acc[64];
#pragma unroll
    for (int o = 0; o < 64; o++) acc[o] = bls[o];
    for (int ck = 0; ck < 30; ck++) {
        float xs = xv[ck];
        const f32x4* wrow = (const f32x4*)(&wls[ck][0]);
#pragma unroll
        for (int o4 = 0; o4 < 16; o4++) {
            f32x4 w4 = wrow[o4];
            acc[o4 * 4 + 0] += xs * w4[0];
            acc[o4 * 4 + 1] += xs * w4[1];
            acc[o4 * 4 + 2] += xs * w4[2];
            acc[o4 * 4 + 3] += xs * w4[3];
        }
    }
    bf16x8 ob[8];
#pragma unroll
    for (int i = 0; i < 8; i++)
#pragma unroll
        for (int e = 0; e < 8; e++)
            ob[i][e] = (bf16)fmaxf(acc[i * 8 + e], 0.0f);
    bf16x8* dst = (bf16x8*)(out + (size_t)p * 64);
#pragma unroll
    for (int i = 0; i < 8; i++) dst[i] = ob[i];
}

// ---------------------------------------------------------------------------
// LDS-free gathered GEMM. Per-lane fragments loaded directly from global.
// Wave tile 32x32 (TO=TP=2), block = 2x2 waves -> 64x64 tile.
// grid = (pos/64, O/64, S). S>1: write fp32 partial slab[z][p*O+o].
// in: [2N][C] bf16, w: [O][10*C] bf16 (r=k*C+c), table: [N][10].
// ---------------------------------------------------------------------------
template<int C>
__global__ __launch_bounds__(256) void conv_g(
    const bf16* __restrict__ in, const bf16* __restrict__ w,
    const float* __restrict__ bias, const int* __restrict__ table,
    bf16* __restrict__ out, float* __restrict__ slab,
    int N, int O, int S, int PO)
{
    constexpr int TO = 2, TP = 2;
    constexpr int CK = C * 10;
    constexpr int CH = C / 32;           // chunks per k

    const int tid = threadIdx.x;
    const int lane = tid & 63;
    const int wid = tid >> 6;
    const int wo = wid & 1, wp = wid >> 1;
    const int l16 = lane & 15, q = lane >> 4;

    const int p0 = blockIdx.x * 64 + wp * 32;
    const int o0 = blockIdx.y * 64 + wo * 32;
    const int z  = blockIdx.z;

    // per-lane gather position per tp
    int nrow[TP], bN[TP];
#pragma unroll
    for (int tp = 0; tp < TP; tp++) {
        int p = p0 + tp * 16 + l16;
        int b = p >= N;
        bN[tp] = b * N;
        nrow[tp] = (p - b * N) * 10;
    }

    // per-lane W row pointers (A operand): row o, elements kt*32 + q*8
    const bf16* wrow[TO];
#pragma unroll
    for (int to = 0; to < TO; to++)
        wrow[to] = w + (size_t)(o0 + to * 16 + l16) * CK + q * 8;

    f32x4 acc[TO][TP];
#pragma unroll
    for (int a = 0; a < TO; a++)
#pragma unroll
        for (int c = 0; c < TP; c++) acc[a][c] = (f32x4){0.f, 0.f, 0.f, 0.f};

    const int chunks = CH * 10;
    const int per = chunks / S;
    int kt = z * per;
    const int kt1 = kt + per;
    int kk = kt / CH;

    while (kt < kt1) {
        // gather row pointers for this k
        const bf16* xrow[TP];
#pragma unroll
        for (int tp = 0; tp < TP; tp++) {
            int r = bN[tp] + table[nrow[tp] + kk];
            xrow[tp] = in + (size_t)r * C + q * 8 - (size_t)kk * C;  // so +kt*32 works
        }
        int ktEnd = (kk + 1) * CH;
        if (ktEnd > kt1) ktEnd = kt1;
#pragma unroll 4
        for (; kt < ktEnd; kt++) {
            bf16x8 af[TO], bfr[TP];
#pragma unroll
            for (int to = 0; to < TO; to++)
                af[to] = *(const bf16x8*)(wrow[to] + kt * 32);
#pragma unroll
            for (int tp = 0; tp < TP; tp++)
                bfr[tp] = *(const bf16x8*)(xrow[tp] + kt * 32);
#pragma unroll
            for (int to = 0; to < TO; to++)
#pragma unroll
                for (int tp = 0; tp < TP; tp++)
                    acc[to][tp] = __builtin_amdgcn_mfma_f32_16x16x32_bf16(
                        af[to], bfr[tp], acc[to][tp], 0, 0, 0);
        }
        kk++;
    }

    if (S == 1) {
#pragma unroll
        for (int to = 0; to < TO; ++to) {
            int ob = o0 + to * 16 + q * 4;
            f32x4 bv = *(const f32x4*)(bias + ob);
#pragma unroll
            for (int tp = 0; tp < TP; ++tp) {
                int p = p0 + tp * 16 + l16;
                union { ushort4 u4; unsigned short s[4]; } pk;
#pragma unroll
                for (int r = 0; r < 4; r++) {
                    float v = fmaxf(acc[to][tp][r] + bv[r], 0.0f);
                    union { bf16 h; unsigned short u; } cc;
                    cc.h = (bf16)v;
                    pk.s[r] = cc.u;
                }
                *(ushort4*)(out + (size_t)p * O + ob) = pk.u4;
            }
        }
    } else {
        float* sb = slab + (size_t)z * PO;
#pragma unroll
        for (int to = 0; to < TO; ++to) {
            int ob = o0 + to * 16 + q * 4;
#pragma unroll
            for (int tp = 0; tp < TP; ++tp) {
                int p = p0 + tp * 16 + l16;
                *(f32x4*)(sb + (size_t)p * O + ob) = acc[to][tp];
            }
        }
    }
}

// reduce S slabs + bias + relu -> bf16
__global__ __launch_bounds__(256) void epi_reduce(
    const float* __restrict__ slab, const float* __restrict__ bias,
    bf16* __restrict__ out, int PO, int Omask, int S)
{
    int t4 = (blockIdx.x * 256 + threadIdx.x) * 4;
    if (t4 >= PO) return;
    f32x4 s = *(const f32x4*)(slab + t4);
    for (int zz = 1; zz < S; zz++)
        s += *(const f32x4*)(slab + (size_t)zz * PO + t4);
    int o = t4 & Omask;
    f32x4 bv = *(const f32x4*)(bias + o);
    union { ushort4 u4; unsigned short e[4]; } pk;
#pragma unroll
    for (int r = 0; r < 4; r++) {
        float v = fmaxf(s[r] + bv[r], 0.0f);
        union { bf16 h; unsigned short u; } cc;
        cc.h = (bf16)v;
        pk.e[r] = cc.u;
    }
    *(ushort4*)((unsigned short*)out + t4) = pk.u4;
}

// ---------------------------------------------------------------------------
// Maxpool (bf16 post-ReLU: unsigned-short compare == float compare)
// ---------------------------------------------------------------------------
__global__ __launch_bounds__(256) void pool_kernel(
    const bf16* __restrict__ in, const int* __restrict__ adj,
    const int* __restrict__ pool, bf16* __restrict__ out,
    int N, int M, int c8shift)
{
    int t = blockIdx.x * 256 + threadIdx.x;
    int total = M << c8shift;
    if (t >= total) return;
    int cc = t & ((1 << c8shift) - 1);
    int j = t >> c8shift;
    int b = blockIdx.y;
    int C = 8 << c8shift;
    int s = pool[j];
    const int* a = adj + s * 4;
    const unsigned short* inu = (const unsigned short*)in;
    size_t base = (size_t)b * N * C + (size_t)cc * 8;
    u16x8 m = *(const u16x8*)(inu + base + (size_t)a[0] * C);
#pragma unroll
    for (int i = 1; i < 4; i++) {
        u16x8 v = *(const u16x8*)(inu + base + (size_t)a[i] * C);
#pragma unroll
        for (int e = 0; e < 8; e++) m[e] = v[e] > m[e] ? v[e] : m[e];
    }
    *(u16x8*)((unsigned short*)out + ((size_t)b * M + j) * C + (size_t)cc * 8) = m;
}

// Final pool: in [2][320][512] bf16 -> out (2,512,80) fp32
__global__ __launch_bounds__(256) void final_pool(
    const bf16* __restrict__ in, const int* __restrict__ adj,
    const int* __restrict__ pool, float* __restrict__ out)
{
    int t = blockIdx.x * 256 + threadIdx.x;
    if (t >= 81920) return;
    int j = t % 80;
    int rest = t / 80;
    int c = rest & 511;
    int b = rest >> 9;
    int s = pool[j];
    const int* a = adj + s * 4;
    float m = 0.0f;
#pragma unroll
    for (int i = 0; i < 4; i++) {
        float v = (float)in[((size_t)b * 320 + a[i]) * 512 + c];
        m = fmaxf(m, v);
    }
    out[t] = m;
}

// ---------------------------------------------------------------------------
extern "C" void kernel_launch(void* const* d_in, const int* in_sizes, int n_in,
                              void* d_out, int out_size, void* d_ws, size_t ws_size,
                              hipStream_t stream)
{
    const float* x = (const float*)d_in[0];
    const int* convT[5]; const int* adjT[5]; const int* poolT[5];
    for (int l = 0; l < 5; l++) {
        convT[l] = (const int*)d_in[1 + 3 * l];
        adjT[l]  = (const int*)d_in[2 + 3 * l];
        poolT[l] = (const int*)d_in[3 + 3 * l];
    }
    const float* W[13]; const float* Bs[13];
    for (int i = 0; i < 13; i++) {
        W[i]  = (const float*)d_in[16 + 2 * i];
        Bs[i] = (const float*)d_in[17 + 2 * i];
    }

    // workspace: [bf16 weights w1..w12 | buf A (21MB) | buf B (21MB)]
    bf16* wbf = (bf16*)d_ws;
    bf16* A  = (bf16*)((char*)d_ws + (size_t)16343040 * 2);
    bf16* Bb = A + 10485760;
    // fp32 split-K slabs live in the unused high region (8MB..18.5MB) of the
    // 21MB output ping-pong buffer (late-level activations use < 2.7MB).
    float* slabA = (float*)((char*)A + (8u << 20));
    float* slabB = (float*)((char*)Bb + (8u << 20));

    static const int woff[13] = {0, 0, 40960, 122880, 286720, 614400, 1269760,
                                 1925120, 3235840, 5857280, 8478720, 11100160, 13721600};

    prep_w<<<dim3((16343040 + 255) / 256), dim3(256), 0, stream>>>(
        W[1], W[2], W[3], W[4], W[5], W[6], W[7], W[8], W[9], W[10], W[11], W[12], wbf);

    conv0_kernel<<<dim3(640), dim3(256), 0, stream>>>(x, W[0], Bs[0], convT[0], A);

    const int PO3 = 2560 * 512;   // level-3 positions * O
    const int PO4 = 640 * 512;    // level-4 positions * O

    // level 0
    conv_g<64><<<dim3(2560, 1, 1), dim3(256), 0, stream>>>(A, wbf + woff[1], Bs[1], convT[0], Bb, nullptr, 81920, 64, 1, 0);
    pool_kernel<<<dim3(640, 2), dim3(256), 0, stream>>>(Bb, adjT[0], poolT[0], A, 81920, 20480, 3);
    // level 1
    conv_g<64><<<dim3(640, 2, 1), dim3(256), 0, stream>>>(A, wbf + woff[2], Bs[2], convT[1], Bb, nullptr, 20480, 128, 1, 0);
    conv_g<128><<<dim3(640, 2, 1), dim3(256), 0, stream>>>(Bb, wbf + woff[3], Bs[3], convT[1], A, nullptr, 20480, 128, 1, 0);
    pool_kernel<<<dim3(320, 2), dim3(256), 0, stream>>>(A, adjT[1], poolT[1], Bb, 20480, 5120, 4);
    // level 2
    conv_g<128><<<dim3(160, 4, 1), dim3(256), 0, stream>>>(Bb, wbf + woff[4], Bs[4], convT[2], A, nullptr, 5120, 256, 1, 0);
    conv_g<256><<<dim3(160, 4, 1), dim3(256), 0, stream>>>(A, wbf + woff[5], Bs[5], convT[2], Bb, nullptr, 5120, 256, 1, 0);
    conv_g<256><<<dim3(160, 4, 1), dim3(256), 0, stream>>>(Bb, wbf + woff[6], Bs[6], convT[2], A, nullptr, 5120, 256, 1, 0);
    pool_kernel<<<dim3(160, 2), dim3(256), 0, stream>>>(A, adjT[2], poolT[2], Bb, 5120, 1280, 5);
    // level 3 (split-K S=2 -> 640 blocks)
    conv_g<256><<<dim3(40, 8, 2), dim3(256), 0, stream>>>(Bb, wbf + woff[7], Bs[7], convT[3], A, slabA, 1280, 512, 2, PO3);
    epi_reduce<<<dim3(PO3 / 1024), dim3(256), 0, stream>>>(slabA, Bs[7], A, PO3, 511, 2);
    conv_g<512><<<dim3(40, 8, 2), dim3(256), 0, stream>>>(A, wbf + woff[8], Bs[8], convT[3], Bb, slabB, 1280, 512, 2, PO3);
    epi_reduce<<<dim3(PO3 / 1024), dim3(256), 0, stream>>>(slabB, Bs[8], Bb, PO3, 511, 2);
    conv_g<512><<<dim3(40, 8, 2), dim3(256), 0, stream>>>(Bb, wbf + woff[9], Bs[9], convT[3], A, slabA, 1280, 512, 2, PO3);
    epi_reduce<<<dim3(PO3 / 1024), dim3(256), 0, stream>>>(slabA, Bs[9], A, PO3, 511, 2);
    pool_kernel<<<dim3(80, 2), dim3(256), 0, stream>>>(A, adjT[3], poolT[3], Bb, 1280, 320, 6);
    // level 4 (split-K S=8 -> 640 blocks)
    conv_g<512><<<dim3(10, 8, 8), dim3(256), 0, stream>>>(Bb, wbf + woff[10], Bs[10], convT[4], A, slabA, 320, 512, 8, PO4);
    epi_reduce<<<dim3(PO4 / 1024), dim3(256), 0, stream>>>(slabA, Bs[10], A, PO4, 511, 8);
    conv_g<512><<<dim3(10, 8, 8), dim3(256), 0, stream>>>(A, wbf + woff[11], Bs[11], convT[4], Bb, slabB, 320, 512, 8, PO4);
    epi_reduce<<<dim3(PO4 / 1024), dim3(256), 0, stream>>>(slabB, Bs[11], Bb, PO4, 511, 8);
    conv_g<512><<<dim3(10, 8, 8), dim3(256), 0, stream>>>(Bb, wbf + woff[12], Bs[12], convT[4], A, slabA, 320, 512, 8, PO4);
    epi_reduce<<<dim3(PO4 / 1024), dim3(256), 0, stream>>>(slabA, Bs[12], A, PO4, 511, 8);

    final_pool<<<dim3(320), dim3(256), 0, stream>>>(A, adjT[4], poolT[4], (float*)d_out);
}

// Round 3
// 556.133 us; speedup vs baseline: 2.1228x; 2.1228x over previous
//
#include <hip/hip_runtime.h>
#include <stdint.h>

typedef __bf16 bf16;
typedef bf16 bf16x8 __attribute__((ext_vector_type(8)));
typedef float f32x4 __attribute__((ext_vector_type(4)));
typedef unsigned short u16x8 __attribute__((ext_vector_type(8)));

__device__ __forceinline__ void gload_lds16(const bf16* g, bf16* l) {
    __builtin_amdgcn_global_load_lds(
        (const __attribute__((address_space(1))) void*)g,
        (__attribute__((address_space(3))) void*)l, 16, 0, 0);
}

// ---------------------------------------------------------------------------
// Prep: convert+transpose weights w1..w12 from fp32 (O,C,K) to bf16 [O][K*C]
// (r = k*C + c ordering)
// ---------------------------------------------------------------------------
template<int C>
__device__ inline void cvt_one(const float* __restrict__ src, bf16* __restrict__ dst,
                               int e, int base) {
    int local = e - base;
    constexpr int CK = C * 10;
    int o = local / CK;
    int rem = local - o * CK;
    int k = rem / C;
    int c = rem & (C - 1);
    dst[e] = (bf16)src[(o * C + c) * 10 + k];
}

__global__ __launch_bounds__(256) void prep_w(
    const float* w1, const float* w2, const float* w3, const float* w4,
    const float* w5, const float* w6, const float* w7, const float* w8,
    const float* w9, const float* w10, const float* w11, const float* w12,
    bf16* __restrict__ dst)
{
    int e = blockIdx.x * 256 + threadIdx.x;
    if (e >= 16343040) return;
    if      (e <    40960) cvt_one< 64>(w1,  dst, e, 0);
    else if (e <   122880) cvt_one< 64>(w2,  dst, e, 40960);
    else if (e <   286720) cvt_one<128>(w3,  dst, e, 122880);
    else if (e <   614400) cvt_one<128>(w4,  dst, e, 286720);
    else if (e <  1269760) cvt_one<256>(w5,  dst, e, 614400);
    else if (e <  1925120) cvt_one<256>(w6,  dst, e, 1269760);
    else if (e <  3235840) cvt_one<256>(w7,  dst, e, 1925120);
    else if (e <  5857280) cvt_one<512>(w8,  dst, e, 3235840);
    else if (e <  8478720) cvt_one<512>(w9,  dst, e, 5857280);
    else if (e < 11100160) cvt_one<512>(w10, dst, e, 8478720);
    else if (e < 13721600) cvt_one<512>(w11, dst, e, 11100160);
    else                   cvt_one<512>(w12, dst, e, 13721600);
}

// ---------------------------------------------------------------------------
// conv0: C=3, K=10, O=64, fp32 VALU. out: [2][81920][64] bf16
// ---------------------------------------------------------------------------
__global__ __launch_bounds__(256) void conv0_kernel(
    const float* __restrict__ x, const float* __restrict__ w0,
    const float* __restrict__ b0, const int* __restrict__ table,
    bf16* __restrict__ out)
{
    const int N = 81920;
    __shared__ float wls[30][64];
    __shared__ float bls[64];
    int tid = threadIdx.x;
    for (int i = tid; i < 1920; i += 256) {
        int o = i / 30, ck = i - o * 30;
        wls[ck][o] = w0[i];
    }
    if (tid < 64) bls[tid] = b0[tid];
    __syncthreads();

    int p = blockIdx.x * 256 + tid;
    int b = p >= N;
    int n = p - b * N;
    int idx[10];
    const int* trow = table + n * 10;
#pragma unroll
    for (int k = 0; k < 10; k++) idx[k] = trow[k];
    float xv[30];
#pragma unroll
    for (int c = 0; c < 3; c++)
#pragma unroll
        for (int k = 0; k < 10; k++)
            xv[c * 10 + k] = x[(b * 3 + c) * N + idx[k]];

    float acc[64];
#pragma unroll
    for (int o = 0; o < 64; o++) acc[o] = bls[o];
    for (int ck = 0; ck < 30; ck++) {
        float xs = xv[ck];
        const f32x4* wrow = (const f32x4*)(&wls[ck][0]);
#pragma unroll
        for (int o4 = 0; o4 < 16; o4++) {
            f32x4 w4 = wrow[o4];
            acc[o4 * 4 + 0] += xs * w4[0];
            acc[o4 * 4 + 1] += xs * w4[1];
            acc[o4 * 4 + 2] += xs * w4[2];
            acc[o4 * 4 + 3] += xs * w4[3];
        }
    }
    bf16x8 ob[8];
#pragma unroll
    for (int i = 0; i < 8; i++)
#pragma unroll
        for (int e = 0; e < 8; e++)
            ob[i][e] = (bf16)fmaxf(acc[i * 8 + e], 0.0f);
    bf16x8* dst = (bf16x8*)(out + (size_t)p * 64);
#pragma unroll
    for (int i = 0; i < 8; i++) dst[i] = ob[i];
}

// ---------------------------------------------------------------------------
// Pipelined gathered GEMM: triple-buffered async global_load_lds staging,
// bare s_barrier + manual vmcnt(4) (never vmcnt(0)) so prefetch stays in
// flight across the barrier. Chunk = 64 channels (128B/row), XOR-swizzled
// segments for bank-conflict-free ds_read_b128. Block 64x64, 2x2 waves.
// ---------------------------------------------------------------------------
template<int C>
__global__ __launch_bounds__(256) void conv_p(
    const bf16* __restrict__ in, const bf16* __restrict__ w,
    const float* __restrict__ bias, const int* __restrict__ table,
    bf16* __restrict__ out, float* __restrict__ slab,
    int N, int O, int S, int PO)
{
    constexpr int CH = C / 64;            // 64-ch chunks per k
    constexpr int CHUNKS = CH * 10;
    constexpr int CK = C * 10;
    __shared__ bf16 Xs[3][64][64];        // [buf][row(pos)][64ch], swizzled segs
    __shared__ bf16 Ws[3][64][64];        // [buf][row(o)][64ch]
    __shared__ int rowoff[64][10];

    const int tid = threadIdx.x;
    const int lane = tid & 63;
    const int wid = tid >> 6;
    const int wo = wid & 1, wp = wid >> 1;
    const int l16 = lane & 15, q = lane >> 4;

    const int p0 = blockIdx.x * 64;
    const int o0 = blockIdx.y * 64;
    const int z = blockIdx.z;

    for (int j = tid; j < 640; j += 256) {
        int pp = j / 10, k = j - pp * 10;
        int p = p0 + pp;
        int b = p >= N;
        int n = p - b * N;
        rowoff[pp][k] = (b * N + table[n * 10 + k]) * C;
    }
    __syncthreads();

    // staging geometry: wave stages rows [wid*16, wid*16+16) of X and W,
    // two issues of 8 rows each. LDS slot s of row r holds global seg s^(r&7).
    int srowv[2], gsegv[2];
    const bf16* wbase[2];
#pragma unroll
    for (int t = 0; t < 2; t++) {
        int row = wid * 16 + t * 8 + (lane >> 3);
        int gs = (lane & 7) ^ (row & 7);
        srowv[t] = row; gsegv[t] = gs;
        wbase[t] = w + (size_t)(o0 + row) * CK + gs * 8;
    }

    const int per = CHUNKS / S;
    const int c0chunk = z * per;

    auto stage = [&](int chunk, int b3) {
        int k = chunk / CH;
        int cofs = (chunk & (CH - 1)) * 64;
#pragma unroll
        for (int t = 0; t < 2; t++) {
            int ro = rowoff[srowv[t]][k];
            gload_lds16(in + ro + cofs + gsegv[t] * 8, &Xs[b3][wid * 16 + t * 8][0]);
            gload_lds16(wbase[t] + chunk * 64, &Ws[b3][wid * 16 + t * 8][0]);
        }
    };

    f32x4 acc[2][2];
#pragma unroll
    for (int a = 0; a < 2; a++)
#pragma unroll
        for (int c = 0; c < 2; c++) acc[a][c] = (f32x4){0.f, 0.f, 0.f, 0.f};

    stage(c0chunk, 0);
    stage(c0chunk + 1, 1);

    const int arow = wo * 32 + l16;       // A rows: + to*16
    const int brow = wp * 32 + l16;       // B rows: + tp*16
    const int sx = l16 & 7;

    int bi = 0, bs = 2;                   // compute buf, stage buf
    for (int i = 0; i < per; i++) {
        asm volatile("s_waitcnt vmcnt(4)" ::: "memory");
        __builtin_amdgcn_s_barrier();
        const bf16* xb = &Xs[bi][0][0];
        const bf16* wb = &Ws[bi][0][0];
#pragma unroll
        for (int ks = 0; ks < 2; ks++) {
            int slot = ((ks * 4 + q) ^ sx) * 8;
            bf16x8 af[2], bfr[2];
#pragma unroll
            for (int to = 0; to < 2; to++)
                af[to] = *(const bf16x8*)(wb + (arow + to * 16) * 64 + slot);
#pragma unroll
            for (int tp = 0; tp < 2; tp++)
                bfr[tp] = *(const bf16x8*)(xb + (brow + tp * 16) * 64 + slot);
#pragma unroll
            for (int to = 0; to < 2; to++)
#pragma unroll
                for (int tp = 0; tp < 2; tp++)
                    acc[to][tp] = __builtin_amdgcn_mfma_f32_16x16x32_bf16(
                        af[to], bfr[tp], acc[to][tp], 0, 0, 0);
        }
        int nx = i + 2 < per ? i + 2 : per - 1;
        stage(c0chunk + nx, bs);
        bi = bi == 2 ? 0 : bi + 1;
        bs = bs == 2 ? 0 : bs + 1;
    }

    if (S == 1) {
#pragma unroll
        for (int to = 0; to < 2; ++to) {
            int ob = o0 + wo * 32 + to * 16 + q * 4;
            f32x4 bv = *(const f32x4*)(bias + ob);
#pragma unroll
            for (int tp = 0; tp < 2; ++tp) {
                int p = p0 + wp * 32 + tp * 16 + l16;
                union { ushort4 u4; unsigned short s[4]; } pk;
#pragma unroll
                for (int r = 0; r < 4; r++) {
                    float v = fmaxf(acc[to][tp][r] + bv[r], 0.0f);
                    union { bf16 h; unsigned short u; } cc;
                    cc.h = (bf16)v;
                    pk.s[r] = cc.u;
                }
                *(ushort4*)(out + (size_t)p * O + ob) = pk.u4;
            }
        }
    } else {
        float* sb = slab + (size_t)z * PO;
#pragma unroll
        for (int to = 0; to < 2; ++to) {
            int ob = o0 + wo * 32 + to * 16 + q * 4;
#pragma unroll
            for (int tp = 0; tp < 2; ++tp) {
                int p = p0 + wp * 32 + tp * 16 + l16;
                *(f32x4*)(sb + (size_t)p * O + ob) = acc[to][tp];
            }
        }
    }
}

// reduce S slabs + bias + relu -> bf16
__global__ __launch_bounds__(256) void epi_reduce(
    const float* __restrict__ slab, const float* __restrict__ bias,
    bf16* __restrict__ out, int PO, int Omask, int S)
{
    int t4 = (blockIdx.x * 256 + threadIdx.x) * 4;
    if (t4 >= PO) return;
    f32x4 s = *(const f32x4*)(slab + t4);
    for (int zz = 1; zz < S; zz++)
        s += *(const f32x4*)(slab + (size_t)zz * PO + t4);
    int o = t4 & Omask;
    f32x4 bv = *(const f32x4*)(bias + o);
    union { ushort4 u4; unsigned short e[4]; } pk;
#pragma unroll
    for (int r = 0; r < 4; r++) {
        float v = fmaxf(s[r] + bv[r], 0.0f);
        union { bf16 h; unsigned short u; } cc;
        cc.h = (bf16)v;
        pk.e[r] = cc.u;
    }
    *(ushort4*)((unsigned short*)out + t4) = pk.u4;
}

// ---------------------------------------------------------------------------
// Maxpool (bf16 post-ReLU: unsigned-short compare == float compare)
// ---------------------------------------------------------------------------
__global__ __launch_bounds__(256) void pool_kernel(
    const bf16* __restrict__ in, const int* __restrict__ adj,
    const int* __restrict__ pool, bf16* __restrict__ out,
    int N, int M, int c8shift)
{
    int t = blockIdx.x * 256 + threadIdx.x;
    int total = M << c8shift;
    if (t >= total) return;
    int cc = t & ((1 << c8shift) - 1);
    int j = t >> c8shift;
    int b = blockIdx.y;
    int C = 8 << c8shift;
    int s = pool[j];
    const int* a = adj + s * 4;
    const unsigned short* inu = (const unsigned short*)in;
    size_t base = (size_t)b * N * C + (size_t)cc * 8;
    u16x8 m = *(const u16x8*)(inu + base + (size_t)a[0] * C);
#pragma unroll
    for (int i = 1; i < 4; i++) {
        u16x8 v = *(const u16x8*)(inu + base + (size_t)a[i] * C);
#pragma unroll
        for (int e = 0; e < 8; e++) m[e] = v[e] > m[e] ? v[e] : m[e];
    }
    *(u16x8*)((unsigned short*)out + ((size_t)b * M + j) * C + (size_t)cc * 8) = m;
}

// Final pool: in [2][320][512] bf16 -> out (2,512,80) fp32
__global__ __launch_bounds__(256) void final_pool(
    const bf16* __restrict__ in, const int* __restrict__ adj,
    const int* __restrict__ pool, float* __restrict__ out)
{
    int t = blockIdx.x * 256 + threadIdx.x;
    if (t >= 81920) return;
    int j = t % 80;
    int rest = t / 80;
    int c = rest & 511;
    int b = rest >> 9;
    int s = pool[j];
    const int* a = adj + s * 4;
    float m = 0.0f;
#pragma unroll
    for (int i = 0; i < 4; i++) {
        float v = (float)in[((size_t)b * 320 + a[i]) * 512 + c];
        m = fmaxf(m, v);
    }
    out[t] = m;
}

// ---------------------------------------------------------------------------
extern "C" void kernel_launch(void* const* d_in, const int* in_sizes, int n_in,
                              void* d_out, int out_size, void* d_ws, size_t ws_size,
                              hipStream_t stream)
{
    const float* x = (const float*)d_in[0];
    const int* convT[5]; const int* adjT[5]; const int* poolT[5];
    for (int l = 0; l < 5; l++) {
        convT[l] = (const int*)d_in[1 + 3 * l];
        adjT[l]  = (const int*)d_in[2 + 3 * l];
        poolT[l] = (const int*)d_in[3 + 3 * l];
    }
    const float* W[13]; const float* Bs[13];
    for (int i = 0; i < 13; i++) {
        W[i]  = (const float*)d_in[16 + 2 * i];
        Bs[i] = (const float*)d_in[17 + 2 * i];
    }

    bf16* wbf = (bf16*)d_ws;
    bf16* A  = (bf16*)((char*)d_ws + (size_t)16343040 * 2);
    bf16* Bb = A + 10485760;
    // split-K fp32 slabs at +6MB inside each 21MB buffer (late-level
    // activations use <2.7MB of the low region)
    float* slabA = (float*)((char*)A + (6u << 20));
    float* slabB = (float*)((char*)Bb + (6u << 20));

    static const int woff[13] = {0, 0, 40960, 122880, 286720, 614400, 1269760,
                                 1925120, 3235840, 5857280, 8478720, 11100160, 13721600};

    prep_w<<<dim3((16343040 + 255) / 256), dim3(256), 0, stream>>>(
        W[1], W[2], W[3], W[4], W[5], W[6], W[7], W[8], W[9], W[10], W[11], W[12], wbf);

    conv0_kernel<<<dim3(640), dim3(256), 0, stream>>>(x, W[0], Bs[0], convT[0], A);

    const int PO3 = 2560 * 512;
    const int PO4 = 640 * 512;

    // level 0
    conv_p<64><<<dim3(2560, 1, 1), dim3(256), 0, stream>>>(A, wbf + woff[1], Bs[1], convT[0], Bb, nullptr, 81920, 64, 1, 0);
    pool_kernel<<<dim3(640, 2), dim3(256), 0, stream>>>(Bb, adjT[0], poolT[0], A, 81920, 20480, 3);
    // level 1
    conv_p<64><<<dim3(640, 2, 1), dim3(256), 0, stream>>>(A, wbf + woff[2], Bs[2], convT[1], Bb, nullptr, 20480, 128, 1, 0);
    conv_p<128><<<dim3(640, 2, 1), dim3(256), 0, stream>>>(Bb, wbf + woff[3], Bs[3], convT[1], A, nullptr, 20480, 128, 1, 0);
    pool_kernel<<<dim3(320, 2), dim3(256), 0, stream>>>(A, adjT[1], poolT[1], Bb, 20480, 5120, 4);
    // level 2
    conv_p<128><<<dim3(160, 4, 1), dim3(256), 0, stream>>>(Bb, wbf + woff[4], Bs[4], convT[2], A, nullptr, 5120, 256, 1, 0);
    conv_p<256><<<dim3(160, 4, 1), dim3(256), 0, stream>>>(A, wbf + woff[5], Bs[5], convT[2], Bb, nullptr, 5120, 256, 1, 0);
    conv_p<256><<<dim3(160, 4, 1), dim3(256), 0, stream>>>(Bb, wbf + woff[6], Bs[6], convT[2], A, nullptr, 5120, 256, 1, 0);
    pool_kernel<<<dim3(160, 2), dim3(256), 0, stream>>>(A, adjT[2], poolT[2], Bb, 5120, 1280, 5);
    // level 3 (split-K S=2 -> 640 blocks)
    conv_p<256><<<dim3(40, 8, 2), dim3(256), 0, stream>>>(Bb, wbf + woff[7], Bs[7], convT[3], nullptr, slabA, 1280, 512, 2, PO3);
    epi_reduce<<<dim3(PO3 / 1024), dim3(256), 0, stream>>>(slabA, Bs[7], A, PO3, 511, 2);
    conv_p<512><<<dim3(40, 8, 2), dim3(256), 0, stream>>>(A, wbf + woff[8], Bs[8], convT[3], nullptr, slabB, 1280, 512, 2, PO3);
    epi_reduce<<<dim3(PO3 / 1024), dim3(256), 0, stream>>>(slabB, Bs[8], Bb, PO3, 511, 2);
    conv_p<512><<<dim3(40, 8, 2), dim3(256), 0, stream>>>(Bb, wbf + woff[9], Bs[9], convT[3], nullptr, slabA, 1280, 512, 2, PO3);
    epi_reduce<<<dim3(PO3 / 1024), dim3(256), 0, stream>>>(slabA, Bs[9], A, PO3, 511, 2);
    pool_kernel<<<dim3(80, 2), dim3(256), 0, stream>>>(A, adjT[3], poolT[3], Bb, 1280, 320, 6);
    // level 4 (split-K S=8 -> 640 blocks)
    conv_p<512><<<dim3(10, 8, 8), dim3(256), 0, stream>>>(Bb, wbf + woff[10], Bs[10], convT[4], nullptr, slabA, 320, 512, 8, PO4);
    epi_reduce<<<dim3(PO4 / 1024), dim3(256), 0, stream>>>(slabA, Bs[10], A, PO4, 511, 8);
    conv_p<512><<<dim3(10, 8, 8), dim3(256), 0, stream>>>(A, wbf + woff[11], Bs[11], convT[4], nullptr, slabB, 320, 512, 8, PO4);
    epi_reduce<<<dim3(PO4 / 1024), dim3(256), 0, stream>>>(slabB, Bs[11], Bb, PO4, 511, 8);
    conv_p<512><<<dim3(10, 8, 8), dim3(256), 0, stream>>>(Bb, wbf + woff[12], Bs[12], convT[4], nullptr, slabA, 320, 512, 8, PO4);
    epi_reduce<<<dim3(PO4 / 1024), dim3(256), 0, stream>>>(slabA, Bs[12], A, PO4, 511, 8);

    final_pool<<<dim3(320), dim3(256), 0, stream>>>(A, adjT[4], poolT[4], (float*)d_out);
}